// Round 1
// baseline (28058.484 us; speedup 1.0000x reference)
//
#include <hip/hip_runtime.h>
#include <cstddef>

#define L 16
#define PLANE (L * L)   // 256
#define VOL (L * L * L * L)

// One block per (n, d1, d2). 256 threads = (d3, d4) plane.
// Per input channel: stage 3x3 halo'd 18x18 planes into LDS, then each
// thread accumulates all OC output channels in registers with weights
// fetched via wave-uniform (scalar) loads.
template <int IC, int OC, bool PRELU>
__global__ __launch_bounds__(256, 4)
void conv4d_kernel(const float* __restrict__ x, const float* __restrict__ w,
                   const float* __restrict__ slopes, int sidx,
                   float* __restrict__ out)
{
    const int blk = blockIdx.x;
    const int d2 = blk & 15;
    const int d1 = (blk >> 4) & 15;
    const int n  = blk >> 8;
    const int tid = threadIdx.x;
    const int c = tid >> 4;   // d3
    const int d = tid & 15;   // d4

    __shared__ float xs[3][3][18][18];

    // Zero entire LDS once: borders correspond to SAME-padding and are
    // never overwritten by the interior staging stores below.
    float* xsf = &xs[0][0][0][0];
    for (int idx = tid; idx < 3 * 3 * 18 * 18; idx += 256) xsf[idx] = 0.0f;

    float acc[OC];
#pragma unroll
    for (int o = 0; o < OC; ++o) acc[o] = 0.0f;

    for (int i = 0; i < IC; ++i) {
        // ---- stage interior of the 9 halo planes for channel i ----
#pragma unroll
        for (int da = 0; da < 3; ++da) {
            const int a = d1 + da - 1;
#pragma unroll
            for (int db = 0; db < 3; ++db) {
                const int b = d2 + db - 1;
                float v = 0.0f;
                if (a >= 0 && a < L && b >= 0 && b < L)
                    v = x[(((size_t)(n * IC + i) * L + a) * L + b) * PLANE
                          + c * L + d];
                xs[da][db][c + 1][d + 1] = v;
            }
        }
        __syncthreads();

        // ---- accumulate: 81 taps x OC channels ----
        // w layout: w[o][i][da][db][dc][dd], o-stride = IC*81
        const float* wi = w + (size_t)i * 81;
#pragma unroll
        for (int da = 0; da < 3; ++da) {
#pragma unroll
            for (int db = 0; db < 3; ++db) {
                const float* wt = wi + (da * 3 + db) * 9;
#pragma unroll
                for (int dc = 0; dc < 3; ++dc) {
#pragma unroll
                    for (int dd = 0; dd < 3; ++dd) {
                        const float v = xs[da][db][c + dc][d + dd];
                        const int t = dc * 3 + dd;
#pragma unroll
                        for (int o = 0; o < OC; ++o)
                            acc[o] = fmaf(v, wt[(size_t)o * IC * 81 + t],
                                          acc[o]);
                    }
                }
            }
        }
        __syncthreads();
    }

    float slope = 0.0f;
    if (PRELU) slope = slopes[sidx];
#pragma unroll
    for (int o = 0; o < OC; ++o) {
        float r = acc[o];
        if (PRELU) r = (r >= 0.0f) ? r : slope * r;
        out[(((size_t)(n * OC + o) * L + d1) * L + d2) * PLANE + c * L + d] = r;
    }
}

extern "C" void kernel_launch(void* const* d_in, const int* in_sizes, int n_in,
                              void* d_out, int out_size, void* d_ws, size_t ws_size,
                              hipStream_t stream)
{
    (void)in_sizes; (void)n_in; (void)out_size; (void)ws_size;
    const float* x      = (const float*)d_in[0];
    const float* k0     = (const float*)d_in[1];
    const float* k1     = (const float*)d_in[2];
    const float* k2     = (const float*)d_in[3];
    const float* k3     = (const float*)d_in[4];
    const float* k4     = (const float*)d_in[5];
    const float* k5     = (const float*)d_in[6];
    const float* slopes = (const float*)d_in[7];
    float* outp = (float*)d_out;

    // Ping-pong hidden buffers: 8 * 32 * 16^4 floats = 64 MB each.
    float* buf0 = (float*)d_ws;
    float* buf1 = buf0 + (size_t)8 * 32 * VOL;

    const dim3 grid(8 * L * L);   // (n, d1, d2)
    const dim3 block(256);        // (d3, d4)

    conv4d_kernel<2, 32, true ><<<grid, block, 0, stream>>>(x,    k0, slopes, 0, buf0);
    conv4d_kernel<32, 32, true><<<grid, block, 0, stream>>>(buf0, k1, slopes, 1, buf1);
    conv4d_kernel<32, 32, true><<<grid, block, 0, stream>>>(buf1, k2, slopes, 2, buf0);
    conv4d_kernel<32, 32, true><<<grid, block, 0, stream>>>(buf0, k3, slopes, 3, buf1);
    conv4d_kernel<32, 32, true><<<grid, block, 0, stream>>>(buf1, k4, slopes, 4, buf0);
    conv4d_kernel<32, 2, false><<<grid, block, 0, stream>>>(buf0, k5, slopes, 0, outp);
}

// Round 2
// 5970.284 us; speedup vs baseline: 4.6997x; 4.6997x over previous
//
#include <hip/hip_runtime.h>
#include <cstddef>

#define L 16
#define PLANE (L * L)   // 256
#define VOL (L * L * L * L)

// ---------------------------------------------------------------------------
// Weight repack: k[o][i][81] (o-major) -> wp[i][tap][o] (o contiguous, 32-wide)
// Packed weights for the 5 OC=32 layers live in d_out (used as scratch; the
// final conv overwrites all of d_out afterwards).
//   layer0: IC=2  -> 5184 floats at offset 0
//   layer1..4: IC=32 -> 82944 floats each, consecutive
// ---------------------------------------------------------------------------
__global__ void pack_weights(const float* __restrict__ k0,
                             const float* __restrict__ k1,
                             const float* __restrict__ k2,
                             const float* __restrict__ k3,
                             const float* __restrict__ k4,
                             float* __restrict__ dst)
{
    const int layer = blockIdx.y;
    const float* src = (layer == 0) ? k0 : (layer == 1) ? k1
                     : (layer == 2) ? k2 : (layer == 3) ? k3 : k4;
    const int IC = (layer == 0) ? 2 : 32;
    const size_t doff = (layer == 0) ? 0 : (size_t)5184 + (size_t)(layer - 1) * 82944;

    const int idx = blockIdx.x * 256 + threadIdx.x;   // = (i*81 + t)*32 + o
    const int total = IC * 81 * 32;
    if (idx >= total) return;
    const int o = idx & 31;
    const int t = (idx >> 5) % 81;
    const int i = idx / (32 * 81);
    dst[doff + idx] = src[((size_t)(o * IC + i)) * 81 + t];
}

// ---------------------------------------------------------------------------
// OC=32 conv layer. One block per (n,d1,d2); 256 threads = (d3,d4).
// Per input channel: stage 3x3 halo'd 18x18 planes to LDS; inner loop does
// 1 LDS activation read per 32 FMAs, weights via wave-uniform scalar loads
// from the packed wp[i][tap][o] layout (contiguous, 16B-aligned -> s_load_x16).
// ---------------------------------------------------------------------------
template <int IC, bool PRELU>
__global__ __launch_bounds__(256, 4)
void conv4d_oc32(const float* __restrict__ x, const float* __restrict__ wp,
                 const float* __restrict__ slopes, int sidx,
                 float* __restrict__ out)
{
    const int blk = blockIdx.x;
    const int d2 = blk & 15;
    const int d1 = (blk >> 4) & 15;
    const int n  = blk >> 8;
    const int tid = threadIdx.x;
    const int c = tid >> 4;   // d3
    const int d = tid & 15;   // d4

    __shared__ float xs[3][3][18][18];

    // Zero once: border cells are the SAME-padding zeros, never overwritten.
    float* xsf = &xs[0][0][0][0];
    for (int idx = tid; idx < 3 * 3 * 18 * 18; idx += 256) xsf[idx] = 0.0f;

    float acc[32];
#pragma unroll
    for (int o = 0; o < 32; ++o) acc[o] = 0.0f;

    for (int i = 0; i < IC; ++i) {
        // ---- stage interior of the 9 halo planes for channel i ----
#pragma unroll
        for (int da = 0; da < 3; ++da) {
            const int a = d1 + da - 1;
#pragma unroll
            for (int db = 0; db < 3; ++db) {
                const int b = d2 + db - 1;
                float v = 0.0f;
                if (a >= 0 && a < L && b >= 0 && b < L)
                    v = x[(((size_t)(n * IC + i) * L + a) * L + b) * PLANE
                          + c * L + d];
                xs[da][db][c + 1][d + 1] = v;
            }
        }
        __syncthreads();

        // ---- accumulate ----
        // wp row for (i, tap p*9+q): wp + ((i*81 + p*9 + q)*32), 32 floats.
        const float* wpi = wp + (size_t)i * 81 * 32;
        // Keep (da,db) as a real loop: body ~3KB, stays I-cache resident.
#pragma unroll 1
        for (int da = 0; da < 3; ++da) {
#pragma unroll 1
            for (int db = 0; db < 3; ++db) {
                // Hoist the 9 shared activation values for this plane.
                float xv[3][3];
#pragma unroll
                for (int dc = 0; dc < 3; ++dc)
#pragma unroll
                    for (int dd = 0; dd < 3; ++dd)
                        xv[dc][dd] = xs[da][db][c + dc][d + dd];

                const float* wt = wpi + (da * 3 + db) * 9 * 32;
#pragma unroll
                for (int dc = 0; dc < 3; ++dc) {
#pragma unroll
                    for (int dd = 0; dd < 3; ++dd) {
                        const float* wr = wt + (dc * 3 + dd) * 32;
#pragma unroll
                        for (int o = 0; o < 32; ++o)
                            acc[o] = fmaf(xv[dc][dd], wr[o], acc[o]);
                    }
                }
            }
        }
        __syncthreads();
    }

    float slope = 0.0f;
    if (PRELU) slope = slopes[sidx];
#pragma unroll
    for (int o = 0; o < 32; ++o) {
        float r = acc[o];
        if (PRELU) r = (r >= 0.0f) ? r : slope * r;
        out[(((size_t)(n * 32 + o) * L + d1) * L + d2) * PLANE + c * L + d] = r;
    }
}

// ---------------------------------------------------------------------------
// Final layer: IC=32, OC=2, no PReLU. Reads ORIGINAL k5 layout (d_out holds
// packed weights until this kernel overwrites it, so k5 must come from d_in).
// ---------------------------------------------------------------------------
__global__ __launch_bounds__(256, 4)
void conv4d_out(const float* __restrict__ x, const float* __restrict__ w,
                float* __restrict__ out)
{
    const int blk = blockIdx.x;
    const int d2 = blk & 15;
    const int d1 = (blk >> 4) & 15;
    const int n  = blk >> 8;
    const int tid = threadIdx.x;
    const int c = tid >> 4;
    const int d = tid & 15;

    __shared__ float xs[3][3][18][18];
    float* xsf = &xs[0][0][0][0];
    for (int idx = tid; idx < 3 * 3 * 18 * 18; idx += 256) xsf[idx] = 0.0f;

    float acc0 = 0.0f, acc1 = 0.0f;

    for (int i = 0; i < 32; ++i) {
#pragma unroll
        for (int da = 0; da < 3; ++da) {
            const int a = d1 + da - 1;
#pragma unroll
            for (int db = 0; db < 3; ++db) {
                const int b = d2 + db - 1;
                float v = 0.0f;
                if (a >= 0 && a < L && b >= 0 && b < L)
                    v = x[(((size_t)(n * 32 + i) * L + a) * L + b) * PLANE
                          + c * L + d];
                xs[da][db][c + 1][d + 1] = v;
            }
        }
        __syncthreads();

        const float* w0 = w + (size_t)(0 * 32 + i) * 81;
        const float* w1 = w + (size_t)(1 * 32 + i) * 81;
#pragma unroll 1
        for (int da = 0; da < 3; ++da) {
#pragma unroll 1
            for (int db = 0; db < 3; ++db) {
                const int off = (da * 3 + db) * 9;
#pragma unroll
                for (int dc = 0; dc < 3; ++dc) {
#pragma unroll
                    for (int dd = 0; dd < 3; ++dd) {
                        const float v = xs[da][db][c + dc][d + dd];
                        acc0 = fmaf(v, w0[off + dc * 3 + dd], acc0);
                        acc1 = fmaf(v, w1[off + dc * 3 + dd], acc1);
                    }
                }
            }
        }
        __syncthreads();
    }

    const size_t base = (((size_t)(n * 2 + 0) * L + d1) * L + d2) * PLANE + c * L + d;
    out[base] = acc0;
    out[base + (size_t)32 * VOL / 32] = acc1;   // stride between o=0 and o=1 planes: VOL
}

extern "C" void kernel_launch(void* const* d_in, const int* in_sizes, int n_in,
                              void* d_out, int out_size, void* d_ws, size_t ws_size,
                              hipStream_t stream)
{
    (void)in_sizes; (void)n_in; (void)out_size; (void)ws_size;
    const float* x      = (const float*)d_in[0];
    const float* k0     = (const float*)d_in[1];
    const float* k1     = (const float*)d_in[2];
    const float* k2     = (const float*)d_in[3];
    const float* k3     = (const float*)d_in[4];
    const float* k4     = (const float*)d_in[5];
    const float* k5     = (const float*)d_in[6];
    const float* slopes = (const float*)d_in[7];
    float* outp = (float*)d_out;

    // Ping-pong hidden buffers: 8 * 32 * 16^4 floats = 64 MB each.
    float* buf0 = (float*)d_ws;
    float* buf1 = buf0 + (size_t)8 * 32 * VOL;

    // Packed weights live in d_out (1.318 MB of the 4 MB output buffer).
    float* wp0 = outp;
    float* wp1 = wp0 + 5184;
    float* wp2 = wp1 + 82944;
    float* wp3 = wp2 + 82944;
    float* wp4 = wp3 + 82944;

    pack_weights<<<dim3(324, 5), 256, 0, stream>>>(k0, k1, k2, k3, k4, outp);

    const dim3 grid(8 * L * L);   // (n, d1, d2)
    const dim3 block(256);        // (d3, d4)

    conv4d_oc32<2,  true ><<<grid, block, 0, stream>>>(x,    wp0, slopes, 0, buf0);
    conv4d_oc32<32, true ><<<grid, block, 0, stream>>>(buf0, wp1, slopes, 1, buf1);
    conv4d_oc32<32, true ><<<grid, block, 0, stream>>>(buf1, wp2, slopes, 2, buf0);
    conv4d_oc32<32, true ><<<grid, block, 0, stream>>>(buf0, wp3, slopes, 3, buf1);
    conv4d_oc32<32, true ><<<grid, block, 0, stream>>>(buf1, wp4, slopes, 4, buf0);
    conv4d_out<<<grid, block, 0, stream>>>(buf0, k5, outp);
}

// Round 3
// 1200.133 us; speedup vs baseline: 23.3795x; 4.9747x over previous
//
#include <hip/hip_runtime.h>
#include <cstddef>

#define L 16
#define PLANE 256
#define VOL 65536

typedef __attribute__((ext_vector_type(8))) short short8;
typedef __attribute__((ext_vector_type(4))) float f32x4;

__device__ __forceinline__ unsigned short f2bf(float f) {
    unsigned u = __builtin_bit_cast(unsigned, f);
    unsigned r = (u + 0x7FFFu + ((u >> 16) & 1u)) >> 16;
    return (unsigned short)r;
}
__device__ __forceinline__ float bf2f(unsigned short h) {
    unsigned u = ((unsigned)h) << 16;
    return __builtin_bit_cast(float, u);
}

// ---------------------------------------------------------------------------
// Pack layer0 (IC=2) weights to fp32 [i][tap][o] for the fp32 kernel.
// ---------------------------------------------------------------------------
__global__ void pack_w0(const float* __restrict__ k0, float* __restrict__ dst)
{
    int idx = blockIdx.x * 256 + threadIdx.x;   // (i*81 + t)*32 + o
    if (idx >= 2 * 81 * 32) return;
    int o = idx & 31;
    int t = (idx >> 5) % 81;
    int i = idx / (32 * 81);
    dst[idx] = k0[(size_t)(o * 2 + i) * 81 + t];
}

// ---------------------------------------------------------------------------
// Split-pack k1..k4 to bf16 hi/lo: wpk[layer][tap][{hi,lo}][n=o 0..31][k=i 0..31]
// tap t = ((da*3+db)*3+dc)*3+dd. Per layer: 81*2048 ushorts.
// ---------------------------------------------------------------------------
__global__ void pack_split(const float* __restrict__ k1, const float* __restrict__ k2,
                           const float* __restrict__ k3, const float* __restrict__ k4,
                           unsigned short* __restrict__ dst)
{
    int idx = blockIdx.x * 256 + threadIdx.x;
    if (idx >= 4 * 81 * 1024) return;
    int layer = idx / (81 * 1024);
    int r = idx % (81 * 1024);
    int t = r / 1024;
    int oi = r % 1024;                  // o*32 + i
    int o = oi >> 5, i = oi & 31;
    const float* src = layer == 0 ? k1 : layer == 1 ? k2 : layer == 2 ? k3 : k4;
    float w = src[(size_t)(o * 32 + i) * 81 + t];
    unsigned short h = f2bf(w);
    unsigned short l = f2bf(w - bf2f(h));
    size_t base = ((size_t)layer * 81 + t) * 2048 + oi;
    dst[base] = h;
    dst[base + 1024] = l;
}

// ---------------------------------------------------------------------------
// MFMA conv layer, IC=OC=32, PReLU. Block = (n,d1,d2); 4 waves.
// Per (da,db): stage halo'd 18x18x32 plane as split bf16 (hi ch0-31 in groups
// 0-3, lo in groups 4-7, XOR-swizzled by column for conflict-free b128), then
// 9 (dc,dd) taps x 3 split passes of mfma_f32_16x16x32_bf16.
// ---------------------------------------------------------------------------
__global__ __launch_bounds__(256, 2)
void conv4d_mfma(const float* __restrict__ x, const unsigned short* __restrict__ wl_,
                 const float* __restrict__ slopes, int sidx, float* __restrict__ out)
{
    const int blk = blockIdx.x;
    const int d2 = blk & 15;
    const int d1 = (blk >> 4) & 15;
    const int n  = blk >> 8;
    const int tid = threadIdx.x;
    const int c = tid >> 4, d = tid & 15;     // staging position (d3,d4)
    const int lane = tid & 63;
    const int wv = tid >> 6;                  // wave id: handles d3 in [4wv,4wv+3]
    const int l15 = lane & 15, q = lane >> 4; // MFMA lane coords

    __shared__ unsigned short as_[18 * 18 * 64];

    {   // zero once: borders are the SAME-padding zeros, never overwritten
        int* p = (int*)as_;
        for (int i = tid; i < 18 * 18 * 32; i += 256) p[i] = 0;
    }

    f32x4 acc[4][2];
#pragma unroll
    for (int f = 0; f < 4; ++f)
#pragma unroll
        for (int nf = 0; nf < 2; ++nf)
            acc[f][nf] = (f32x4){0.f, 0.f, 0.f, 0.f};

#pragma unroll 1
    for (int da = 0; da < 3; ++da) {
        const int a = d1 + da - 1;
#pragma unroll 1
        for (int db = 0; db < 3; ++db) {
            const int b = d2 + db - 1;
            // OOB plane == all zeros: its 9 taps contribute nothing; skip.
            if (a < 0 || a > 15 || b < 0 || b > 15) continue;   // block-uniform
            __syncthreads();   // previous taps done reading LDS
            // ---- stage plane (a,b): fp32 -> split bf16 hi/lo ----
            {
                const float* src = x + (size_t)n * 32 * VOL + (size_t)(a * 16 + b) * PLANE + tid;
                const int colw = d + 1;
                unsigned short* basep = &as_[((c + 1) * 18 + colw) * 64];
#pragma unroll
                for (int g = 0; g < 4; ++g) {
                    float v[8];
#pragma unroll
                    for (int j = 0; j < 8; ++j) v[j] = src[(size_t)(g * 8 + j) * VOL];
                    short8 hi, lo;
#pragma unroll
                    for (int j = 0; j < 8; ++j) {
                        unsigned short h = f2bf(v[j]);
                        hi[j] = (short)h;
                        lo[j] = (short)f2bf(v[j] - bf2f(h));
                    }
                    *(short8*)(basep + ((g ^ (colw & 7)) * 8)) = hi;
                    *(short8*)(basep + (((g + 4) ^ (colw & 7)) * 8)) = lo;
                }
            }
            __syncthreads();
            // ---- 9 taps for this (da,db) ----
            const unsigned short* wt0 = wl_ + (size_t)((da * 3 + db) * 9) * 2048;
#pragma unroll 1
            for (int dc = 0; dc < 3; ++dc) {
#pragma unroll 1
                for (int dd = 0; dd < 3; ++dd) {
                    const unsigned short* wb = wt0 + (dc * 3 + dd) * 2048;
                    // B frags: B[k=q*8+j][n=nf*16+l15]; packed as [n][k] k-contig
                    short8 bh0 = *(const short8*)(wb + l15 * 32 + q * 8);
                    short8 bh1 = *(const short8*)(wb + (16 + l15) * 32 + q * 8);
                    short8 bl0 = *(const short8*)(wb + 1024 + l15 * 32 + q * 8);
                    short8 bl1 = *(const short8*)(wb + 1024 + (16 + l15) * 32 + q * 8);
                    const int col = l15 + dd;           // d4 + dd
                    const int sw_h = (q ^ (col & 7)) * 8;
                    const int sw_l = ((q + 4) ^ (col & 7)) * 8;
                    short8 ah[4], al[4];
#pragma unroll
                    for (int f = 0; f < 4; ++f) {
                        const unsigned short* ab = &as_[(((wv * 4 + f) + dc) * 18 + col) * 64];
                        ah[f] = *(const short8*)(ab + sw_h);
                        al[f] = *(const short8*)(ab + sw_l);
                    }
                    // 3 split passes, 8 independent acc chains each
#pragma unroll
                    for (int f = 0; f < 4; ++f) {
                        acc[f][0] = __builtin_amdgcn_mfma_f32_16x16x32_bf16(ah[f], bh0, acc[f][0], 0, 0, 0);
                        acc[f][1] = __builtin_amdgcn_mfma_f32_16x16x32_bf16(ah[f], bh1, acc[f][1], 0, 0, 0);
                    }
#pragma unroll
                    for (int f = 0; f < 4; ++f) {
                        acc[f][0] = __builtin_amdgcn_mfma_f32_16x16x32_bf16(ah[f], bl0, acc[f][0], 0, 0, 0);
                        acc[f][1] = __builtin_amdgcn_mfma_f32_16x16x32_bf16(ah[f], bl1, acc[f][1], 0, 0, 0);
                    }
#pragma unroll
                    for (int f = 0; f < 4; ++f) {
                        acc[f][0] = __builtin_amdgcn_mfma_f32_16x16x32_bf16(al[f], bh0, acc[f][0], 0, 0, 0);
                        acc[f][1] = __builtin_amdgcn_mfma_f32_16x16x32_bf16(al[f], bh1, acc[f][1], 0, 0, 0);
                    }
                }
            }
        }
    }

    // ---- epilogue: PReLU + store. D: col=n=l15, row=m(d4)=q*4+reg ----
    const float slope = slopes[sidx];
#pragma unroll
    for (int f = 0; f < 4; ++f) {
        const int d3 = wv * 4 + f;
#pragma unroll
        for (int nf = 0; nf < 2; ++nf) {
            const int o = nf * 16 + l15;
            f32x4 v = acc[f][nf];
#pragma unroll
            for (int j = 0; j < 4; ++j) v[j] = v[j] >= 0.f ? v[j] : slope * v[j];
            float* op = out + ((size_t)(n * 32 + o) * PLANE + (size_t)(d1 * 16 + d2)) * PLANE
                        + d3 * 16 + q * 4;
            *(f32x4*)op = v;
        }
    }
}

// ---------------------------------------------------------------------------
// fp32 layer (used for layer0, IC=2): round-2 proven kernel.
// ---------------------------------------------------------------------------
template <int IC, bool PRELU>
__global__ __launch_bounds__(256, 4)
void conv4d_oc32(const float* __restrict__ x, const float* __restrict__ wp,
                 const float* __restrict__ slopes, int sidx,
                 float* __restrict__ out)
{
    const int blk = blockIdx.x;
    const int d2 = blk & 15;
    const int d1 = (blk >> 4) & 15;
    const int n  = blk >> 8;
    const int tid = threadIdx.x;
    const int c = tid >> 4;
    const int d = tid & 15;

    __shared__ float xs[3][3][18][18];
    float* xsf = &xs[0][0][0][0];
    for (int idx = tid; idx < 3 * 3 * 18 * 18; idx += 256) xsf[idx] = 0.0f;

    float acc[32];
#pragma unroll
    for (int o = 0; o < 32; ++o) acc[o] = 0.0f;

    for (int i = 0; i < IC; ++i) {
#pragma unroll
        for (int da = 0; da < 3; ++da) {
            const int a = d1 + da - 1;
#pragma unroll
            for (int db = 0; db < 3; ++db) {
                const int b = d2 + db - 1;
                float v = 0.0f;
                if (a >= 0 && a < L && b >= 0 && b < L)
                    v = x[(((size_t)(n * IC + i) * L + a) * L + b) * PLANE + c * L + d];
                xs[da][db][c + 1][d + 1] = v;
            }
        }
        __syncthreads();

        const float* wpi = wp + (size_t)i * 81 * 32;
#pragma unroll 1
        for (int da = 0; da < 3; ++da) {
#pragma unroll 1
            for (int db = 0; db < 3; ++db) {
                float xv[3][3];
#pragma unroll
                for (int dc = 0; dc < 3; ++dc)
#pragma unroll
                    for (int dd = 0; dd < 3; ++dd)
                        xv[dc][dd] = xs[da][db][c + dc][d + dd];

                const float* wt = wpi + (da * 3 + db) * 9 * 32;
#pragma unroll
                for (int dc = 0; dc < 3; ++dc) {
#pragma unroll
                    for (int dd = 0; dd < 3; ++dd) {
                        const float* wr = wt + (dc * 3 + dd) * 32;
#pragma unroll
                        for (int o = 0; o < 32; ++o)
                            acc[o] = fmaf(xv[dc][dd], wr[o], acc[o]);
                    }
                }
            }
        }
        __syncthreads();
    }

    float slope = 0.0f;
    if (PRELU) slope = slopes[sidx];
#pragma unroll
    for (int o = 0; o < 32; ++o) {
        float r = acc[o];
        if (PRELU) r = (r >= 0.0f) ? r : slope * r;
        out[(((size_t)(n * 32 + o) * L + d1) * L + d2) * PLANE + c * L + d] = r;
    }
}

// ---------------------------------------------------------------------------
// Final layer: IC=32, OC=2, no PReLU, original k5 layout via scalar loads.
// ---------------------------------------------------------------------------
__global__ __launch_bounds__(256, 4)
void conv4d_out(const float* __restrict__ x, const float* __restrict__ w,
                float* __restrict__ out)
{
    const int blk = blockIdx.x;
    const int d2 = blk & 15;
    const int d1 = (blk >> 4) & 15;
    const int n  = blk >> 8;
    const int tid = threadIdx.x;
    const int c = tid >> 4;
    const int d = tid & 15;

    __shared__ float xs[3][3][18][18];
    float* xsf = &xs[0][0][0][0];
    for (int idx = tid; idx < 3 * 3 * 18 * 18; idx += 256) xsf[idx] = 0.0f;

    float acc0 = 0.0f, acc1 = 0.0f;

    for (int i = 0; i < 32; ++i) {
#pragma unroll
        for (int da = 0; da < 3; ++da) {
            const int a = d1 + da - 1;
#pragma unroll
            for (int db = 0; db < 3; ++db) {
                const int b = d2 + db - 1;
                float v = 0.0f;
                if (a >= 0 && a < L && b >= 0 && b < L)
                    v = x[(((size_t)(n * 32 + i) * L + a) * L + b) * PLANE + c * L + d];
                xs[da][db][c + 1][d + 1] = v;
            }
        }
        __syncthreads();

        const float* w0 = w + (size_t)(0 * 32 + i) * 81;
        const float* w1 = w + (size_t)(1 * 32 + i) * 81;
#pragma unroll 1
        for (int da = 0; da < 3; ++da) {
#pragma unroll 1
            for (int db = 0; db < 3; ++db) {
                const int off = (da * 3 + db) * 9;
#pragma unroll
                for (int dc = 0; dc < 3; ++dc) {
#pragma unroll
                    for (int dd = 0; dd < 3; ++dd) {
                        const float v = xs[da][db][c + dc][d + dd];
                        acc0 = fmaf(v, w0[off + dc * 3 + dd], acc0);
                        acc1 = fmaf(v, w1[off + dc * 3 + dd], acc1);
                    }
                }
            }
        }
        __syncthreads();
    }

    const size_t base = (((size_t)(n * 2 + 0) * L + d1) * L + d2) * PLANE + c * L + d;
    out[base] = acc0;
    out[base + VOL] = acc1;
}

extern "C" void kernel_launch(void* const* d_in, const int* in_sizes, int n_in,
                              void* d_out, int out_size, void* d_ws, size_t ws_size,
                              hipStream_t stream)
{
    (void)in_sizes; (void)n_in; (void)out_size; (void)ws_size;
    const float* x      = (const float*)d_in[0];
    const float* k0     = (const float*)d_in[1];
    const float* k1     = (const float*)d_in[2];
    const float* k2     = (const float*)d_in[3];
    const float* k3     = (const float*)d_in[4];
    const float* k4     = (const float*)d_in[5];
    const float* k5     = (const float*)d_in[6];
    const float* slopes = (const float*)d_in[7];
    float* outp = (float*)d_out;

    // Ping-pong hidden buffers in d_ws: 64 MB each.
    float* buf0 = (float*)d_ws;
    float* buf1 = buf0 + (size_t)8 * 32 * VOL;

    // Scratch weights in d_out (overwritten by the final conv):
    //   wpk: 4 layers * 81 taps * 2048 bf16 = 663552 ushorts = 331776 floats
    //   wp0: 5184 fp32 after that
    unsigned short* wpk = (unsigned short*)d_out;
    float* wp0 = outp + 331776;

    pack_split<<<dim3(1296), 256, 0, stream>>>(k1, k2, k3, k4, wpk);
    pack_w0<<<dim3(21), 256, 0, stream>>>(k0, wp0);

    const dim3 grid(8 * L * L);   // (n, d1, d2)
    const dim3 block(256);

    conv4d_oc32<2, true><<<grid, block, 0, stream>>>(x, wp0, slopes, 0, buf0);
    conv4d_mfma<<<grid, block, 0, stream>>>(buf0, wpk + (size_t)0 * 81 * 2048, slopes, 1, buf1);
    conv4d_mfma<<<grid, block, 0, stream>>>(buf1, wpk + (size_t)1 * 81 * 2048, slopes, 2, buf0);
    conv4d_mfma<<<grid, block, 0, stream>>>(buf0, wpk + (size_t)2 * 81 * 2048, slopes, 3, buf1);
    conv4d_mfma<<<grid, block, 0, stream>>>(buf1, wpk + (size_t)3 * 81 * 2048, slopes, 4, buf0);
    conv4d_out<<<grid, block, 0, stream>>>(buf0, k5, outp);
}

// Round 4
// 1149.018 us; speedup vs baseline: 24.4195x; 1.0445x over previous
//
#include <hip/hip_runtime.h>
#include <cstddef>

#define L 16
#define PLANE 256
#define VOL 65536

typedef __attribute__((ext_vector_type(8))) short short8;
typedef __attribute__((ext_vector_type(4))) float f32x4;
typedef __attribute__((ext_vector_type(4))) unsigned int u32x4;
typedef unsigned int u32;
typedef unsigned short u16;

__device__ __forceinline__ u16 f2bf(float f) {
    u32 u = __builtin_bit_cast(u32, f);
    return (u16)((u + 0x7FFFu + ((u >> 16) & 1u)) >> 16);
}
__device__ __forceinline__ float bf2f(u16 h) {
    u32 u = ((u32)h) << 16;
    return __builtin_bit_cast(float, u);
}
__device__ __forceinline__ u32 packsplit(float v) {
    u16 h = f2bf(v);
    u16 l = f2bf(v - bf2f(h));
    return (u32)h | ((u32)l << 16);
}
__device__ __forceinline__ float unpacksplit(u32 u) {
    float fh = __builtin_bit_cast(float, u << 16);
    float fl = __builtin_bit_cast(float, u & 0xFFFF0000u);
    return fh + fl;
}

// ---------------------------------------------------------------------------
// Pack layer0 (IC=2) weights to fp32 [i][tap][o].
// ---------------------------------------------------------------------------
__global__ void pack_w0(const float* __restrict__ k0, float* __restrict__ dst)
{
    int idx = blockIdx.x * 256 + threadIdx.x;   // (i*81 + t)*32 + o
    if (idx >= 2 * 81 * 32) return;
    int o = idx & 31;
    int t = (idx >> 5) % 81;
    int i = idx / (32 * 81);
    dst[idx] = k0[(size_t)(o * 2 + i) * 81 + t];
}

// ---------------------------------------------------------------------------
// Split-pack k1..k4: wpk[layer][tap][{hi,lo}][n=o][k=i], 81*2048 u16 per layer.
// ---------------------------------------------------------------------------
__global__ void pack_split(const float* __restrict__ k1, const float* __restrict__ k2,
                           const float* __restrict__ k3, const float* __restrict__ k4,
                           u16* __restrict__ dst)
{
    int idx = blockIdx.x * 256 + threadIdx.x;
    if (idx >= 4 * 81 * 1024) return;
    int layer = idx / (81 * 1024);
    int r = idx % (81 * 1024);
    int t = r / 1024;
    int oi = r % 1024;                  // o*32 + i
    int o = oi >> 5, i = oi & 31;
    const float* src = layer == 0 ? k1 : layer == 1 ? k2 : layer == 2 ? k3 : k4;
    float w = src[(size_t)(o * 32 + i) * 81 + t];
    u16 h = f2bf(w);
    u16 l = f2bf(w - bf2f(h));
    size_t base = ((size_t)layer * 81 + t) * 2048 + oi;
    dst[base] = h;
    dst[base + 1024] = l;
}

// ---------------------------------------------------------------------------
// MFMA conv layer, IC=OC=32, PReLU. Activations packed u32 (bf16 hi|lo<<16)
// in [n][d1][d2][ch][d3d4] layout. All 9 (da,db) planes processed (zeros for
// OOB); next plane prefetched into registers during the tap block.
// ---------------------------------------------------------------------------
__global__ __launch_bounds__(256, 3)
void conv4d_mfma(const u32* __restrict__ xb, const u16* __restrict__ wl_,
                 const float* __restrict__ slopes, int sidx, u32* __restrict__ yb)
{
    const int blk = blockIdx.x;
    const int d2 = blk & 15, d1 = (blk >> 4) & 15, n = blk >> 8;
    const int tid = threadIdx.x;
    const int c = tid >> 4, d = tid & 15;
    const int lane = tid & 63, wv = tid >> 6;
    const int l15 = lane & 15, q = lane >> 4;

    __shared__ __attribute__((aligned(16))) u16 as_[18 * 18 * 64];
    { int* p = (int*)as_; for (int i = tid; i < 18 * 18 * 32; i += 256) p[i] = 0; }

    f32x4 acc[4][2];
#pragma unroll
    for (int f = 0; f < 4; ++f)
#pragma unroll
        for (int nf = 0; nf < 2; ++nf)
            acc[f][nf] = (f32x4){0.f, 0.f, 0.f, 0.f};

    const u32* xbase = xb + (size_t)n * 256 * 8192 + tid;

    u32 r[32];
    {   // prefetch plane 0: (da,db)=(0,0) -> (a,b)=(d1-1,d2-1)
        int a = d1 - 1, b = d2 - 1;
        if (a >= 0 && b >= 0) {
            const u32* s = xbase + (size_t)(a * 16 + b) * 8192;
#pragma unroll
            for (int i = 0; i < 32; ++i) r[i] = s[i * 256];
        } else {
#pragma unroll
            for (int i = 0; i < 32; ++i) r[i] = 0;
        }
    }

    const int cw = (d + 1) & 7;
    u16* basep = &as_[((c + 1) * 18 + (d + 1)) * 64];

#pragma unroll 1
    for (int p = 0; p < 9; ++p) {
        __syncthreads();          // prior taps done reading LDS (also drains prefetch)
        // ---- unpack r -> LDS (hi groups 0-3, lo groups 4-7, XOR swizzle) ----
#pragma unroll
        for (int g = 0; g < 4; ++g) {
            short8 hi, lo;
#pragma unroll
            for (int j = 0; j < 8; ++j) {
                u32 u = r[g * 8 + j];
                hi[j] = (short)(u & 0xFFFFu);
                lo[j] = (short)(u >> 16);
            }
            *(short8*)(basep + ((g ^ cw) * 8)) = hi;
            *(short8*)(basep + (((g + 4) ^ cw) * 8)) = lo;
        }
        __syncthreads();
        // ---- prefetch plane p+1 (in flight across the taps below) ----
        if (p < 8) {
            int pn = p + 1;
            int da = (pn * 11) >> 5, db = pn - da * 3;
            int a = d1 + da - 1, b = d2 + db - 1;
            if (a >= 0 && a < 16 && b >= 0 && b < 16) {
                const u32* s = xbase + (size_t)(a * 16 + b) * 8192;
#pragma unroll
                for (int i = 0; i < 32; ++i) r[i] = s[i * 256];
            } else {
#pragma unroll
                for (int i = 0; i < 32; ++i) r[i] = 0;
            }
        }

        // ---- 9 taps for plane p; A-frag rows shared across dc ----
        const u16* wt0 = wl_ + (size_t)p * 9 * 2048;
#pragma unroll 1
        for (int dd = 0; dd < 3; ++dd) {
            const int col = l15 + dd;
            const int sh = (q ^ (col & 7)) * 8;
            const int sl = ((q + 4) ^ (col & 7)) * 8;
            short8 ah[6], al[6];
#pragma unroll
            for (int r6 = 0; r6 < 6; ++r6) {
                const u16* ab = &as_[((wv * 4 + r6) * 18 + col) * 64];
                ah[r6] = *(const short8*)(ab + sh);
                al[r6] = *(const short8*)(ab + sl);
            }
#pragma unroll
            for (int dc = 0; dc < 3; ++dc) {
                const u16* wb = wt0 + (dc * 3 + dd) * 2048;
                short8 bh0 = *(const short8*)(wb + l15 * 32 + q * 8);
                short8 bh1 = *(const short8*)(wb + (16 + l15) * 32 + q * 8);
                short8 bl0 = *(const short8*)(wb + 1024 + l15 * 32 + q * 8);
                short8 bl1 = *(const short8*)(wb + 1024 + (16 + l15) * 32 + q * 8);
#pragma unroll
                for (int f = 0; f < 4; ++f) {
                    acc[f][0] = __builtin_amdgcn_mfma_f32_16x16x32_bf16(ah[f + dc], bh0, acc[f][0], 0, 0, 0);
                    acc[f][1] = __builtin_amdgcn_mfma_f32_16x16x32_bf16(ah[f + dc], bh1, acc[f][1], 0, 0, 0);
                }
#pragma unroll
                for (int f = 0; f < 4; ++f) {
                    acc[f][0] = __builtin_amdgcn_mfma_f32_16x16x32_bf16(ah[f + dc], bl0, acc[f][0], 0, 0, 0);
                    acc[f][1] = __builtin_amdgcn_mfma_f32_16x16x32_bf16(ah[f + dc], bl1, acc[f][1], 0, 0, 0);
                }
#pragma unroll
                for (int f = 0; f < 4; ++f) {
                    acc[f][0] = __builtin_amdgcn_mfma_f32_16x16x32_bf16(al[f + dc], bh0, acc[f][0], 0, 0, 0);
                    acc[f][1] = __builtin_amdgcn_mfma_f32_16x16x32_bf16(al[f + dc], bh1, acc[f][1], 0, 0, 0);
                }
            }
        }
    }

    // ---- epilogue: PReLU, pack split, store dwordx4 (lines fully covered) ----
    const float slope = slopes[sidx];
    u32* ob = yb + (size_t)(n * 256 + d1 * 16 + d2) * 8192;
#pragma unroll
    for (int f = 0; f < 4; ++f) {
#pragma unroll
        for (int nf = 0; nf < 2; ++nf) {
            const int o = nf * 16 + l15;
            u32x4 u;
#pragma unroll
            for (int j = 0; j < 4; ++j) {
                float v = acc[f][nf][j];
                v = v >= 0.f ? v : slope * v;
                u[j] = packsplit(v);
            }
            *(u32x4*)(ob + o * 256 + (wv * 4 + f) * 16 + q * 4) = u;
        }
    }
}

// ---------------------------------------------------------------------------
// Layer 0: IC=2, fp32 math, PReLU; reads original x layout, writes packed u32.
// ---------------------------------------------------------------------------
__global__ __launch_bounds__(256, 4)
void conv4d_c2(const float* __restrict__ x, const float* __restrict__ wp,
               const float* __restrict__ slopes, u32* __restrict__ yb)
{
    const int blk = blockIdx.x;
    const int d2 = blk & 15, d1 = (blk >> 4) & 15, n = blk >> 8;
    const int tid = threadIdx.x;
    const int c = tid >> 4, d = tid & 15;

    __shared__ float xs[3][3][18][18];
    float* xsf = &xs[0][0][0][0];
    for (int idx = tid; idx < 3 * 3 * 18 * 18; idx += 256) xsf[idx] = 0.0f;

    float acc[32];
#pragma unroll
    for (int o = 0; o < 32; ++o) acc[o] = 0.0f;

    for (int i = 0; i < 2; ++i) {
#pragma unroll
        for (int da = 0; da < 3; ++da) {
            const int a = d1 + da - 1;
#pragma unroll
            for (int db = 0; db < 3; ++db) {
                const int b = d2 + db - 1;
                float v = 0.0f;
                if (a >= 0 && a < L && b >= 0 && b < L)
                    v = x[(((size_t)(n * 2 + i) * L + a) * L + b) * PLANE + c * L + d];
                xs[da][db][c + 1][d + 1] = v;
            }
        }
        __syncthreads();

        const float* wpi = wp + (size_t)i * 81 * 32;
#pragma unroll 1
        for (int da = 0; da < 3; ++da) {
#pragma unroll 1
            for (int db = 0; db < 3; ++db) {
                float xv[3][3];
#pragma unroll
                for (int dc = 0; dc < 3; ++dc)
#pragma unroll
                    for (int dd = 0; dd < 3; ++dd)
                        xv[dc][dd] = xs[da][db][c + dc][d + dd];

                const float* wt = wpi + (da * 3 + db) * 9 * 32;
#pragma unroll
                for (int dc = 0; dc < 3; ++dc) {
#pragma unroll
                    for (int dd = 0; dd < 3; ++dd) {
                        const float* wr = wt + (dc * 3 + dd) * 32;
#pragma unroll
                        for (int o = 0; o < 32; ++o)
                            acc[o] = fmaf(xv[dc][dd], wr[o], acc[o]);
                    }
                }
            }
        }
        __syncthreads();
    }

    const float slope = slopes[0];
    u32* ob = yb + (size_t)(n * 256 + d1 * 16 + d2) * 8192;
#pragma unroll
    for (int o = 0; o < 32; ++o) {
        float v = acc[o];
        v = v >= 0.f ? v : slope * v;
        ob[o * 256 + tid] = packsplit(v);
    }
}

// ---------------------------------------------------------------------------
// Final layer: IC=32, OC=2, no PReLU. Packed u32 input, plane-outer with
// register prefetch; weights from original k5 layout (wave-uniform s_loads).
// ---------------------------------------------------------------------------
__global__ __launch_bounds__(256, 3)
void conv4d_out(const u32* __restrict__ xb, const float* __restrict__ k5,
                float* __restrict__ out)
{
    const int blk = blockIdx.x;
    const int d2 = blk & 15, d1 = (blk >> 4) & 15, n = blk >> 8;
    const int tid = threadIdx.x;
    const int c = tid >> 4, d = tid & 15;

    __shared__ float xs2[32 * 324];   // [ch][18*18]
    for (int i = tid; i < 32 * 324; i += 256) xs2[i] = 0.0f;

    const u32* xbase = xb + (size_t)n * 256 * 8192 + tid;

    u32 r[32];
    {
        int a = d1 - 1, b = d2 - 1;
        if (a >= 0 && b >= 0) {
            const u32* s = xbase + (size_t)(a * 16 + b) * 8192;
#pragma unroll
            for (int i = 0; i < 32; ++i) r[i] = s[i * 256];
        } else {
#pragma unroll
            for (int i = 0; i < 32; ++i) r[i] = 0;
        }
    }

    float acc0 = 0.0f, acc1 = 0.0f;
    const int wpos = (c + 1) * 18 + (d + 1);

#pragma unroll 1
    for (int p = 0; p < 9; ++p) {
        __syncthreads();
#pragma unroll
        for (int i = 0; i < 32; ++i) xs2[i * 324 + wpos] = unpacksplit(r[i]);
        __syncthreads();
        if (p < 8) {
            int pn = p + 1;
            int da = (pn * 11) >> 5, db = pn - da * 3;
            int a = d1 + da - 1, b = d2 + db - 1;
            if (a >= 0 && a < 16 && b >= 0 && b < 16) {
                const u32* s = xbase + (size_t)(a * 16 + b) * 8192;
#pragma unroll
                for (int i = 0; i < 32; ++i) r[i] = s[i * 256];
            } else {
#pragma unroll
                for (int i = 0; i < 32; ++i) r[i] = 0;
            }
        }

#pragma unroll 1
        for (int dc = 0; dc < 3; ++dc) {
#pragma unroll 1
            for (int dd = 0; dd < 3; ++dd) {
                const int tap = p * 9 + dc * 3 + dd;
                const int rpos = (c + dc) * 18 + (d + dd);
#pragma unroll
                for (int i = 0; i < 32; ++i) {
                    const float v = xs2[i * 324 + rpos];
                    acc0 = fmaf(v, k5[i * 81 + tap], acc0);
                    acc1 = fmaf(v, k5[(32 + i) * 81 + tap], acc1);
                }
            }
        }
    }

    const size_t base = (size_t)(n * 2) * VOL + (size_t)(d1 * 16 + d2) * 256 + tid;
    out[base] = acc0;
    out[base + VOL] = acc1;
}

extern "C" void kernel_launch(void* const* d_in, const int* in_sizes, int n_in,
                              void* d_out, int out_size, void* d_ws, size_t ws_size,
                              hipStream_t stream)
{
    (void)in_sizes; (void)n_in; (void)out_size; (void)ws_size;
    const float* x      = (const float*)d_in[0];
    const float* k0     = (const float*)d_in[1];
    const float* k1     = (const float*)d_in[2];
    const float* k2     = (const float*)d_in[3];
    const float* k3     = (const float*)d_in[4];
    const float* k4     = (const float*)d_in[5];
    const float* k5     = (const float*)d_in[6];
    const float* slopes = (const float*)d_in[7];
    float* outp = (float*)d_out;

    // Ping-pong packed activation buffers in d_ws: 64 MB each.
    u32* buf0 = (u32*)d_ws;
    u32* buf1 = buf0 + (size_t)8 * 256 * 8192;

    // Scratch weights in d_out (overwritten by the final conv):
    u16* wpk = (u16*)d_out;                 // 663552 u16 = 1.33 MB
    float* wp0 = outp + 331776;             // 5184 fp32 after that

    pack_split<<<dim3(1296), 256, 0, stream>>>(k1, k2, k3, k4, wpk);
    pack_w0<<<dim3(21), 256, 0, stream>>>(k0, wp0);

    const dim3 grid(8 * L * L);   // (n, d1, d2)
    const dim3 block(256);

    conv4d_c2<<<grid, block, 0, stream>>>(x, wp0, slopes, buf0);
    conv4d_mfma<<<grid, block, 0, stream>>>(buf0, wpk + (size_t)0 * 81 * 2048, slopes, 1, buf1);
    conv4d_mfma<<<grid, block, 0, stream>>>(buf1, wpk + (size_t)1 * 81 * 2048, slopes, 2, buf0);
    conv4d_mfma<<<grid, block, 0, stream>>>(buf0, wpk + (size_t)2 * 81 * 2048, slopes, 3, buf1);
    conv4d_mfma<<<grid, block, 0, stream>>>(buf1, wpk + (size_t)3 * 81 * 2048, slopes, 4, buf0);
    conv4d_out<<<grid, block, 0, stream>>>(buf0, k5, outp);
}